// Round 4
// baseline (180.000 us; speedup 1.0000x reference)
//
#include <hip/hip_runtime.h>
#include <hip/hip_cooperative_groups.h>

namespace cg = cooperative_groups;

#define SR   9
#define SD   19
#define TW   16                 // tile width (pixels)
#define TH   6                  // tile height (pixels)
#define LW   (TW + 2*SR)        // 34 staged cols
#define LH   (TH + 2*SR)        // 24 staged rows
#define LS   40                 // LDS row stride; 40 % 32 == 8 -> low-conflict b64 reads
#define IMG  192
#define NPIX (IMG*IMG)

// One cooperative kernel runs all 3 mean-shift iterations with grid-wide
// syncs between them. 768 blocks = exactly 3 per CU (perfect balance);
// __launch_bounds__(192,4) caps VGPRs at 128 so >=5 blocks/CU fit ->
// cooperative co-residency validation passes with margin.
__global__ __launch_bounds__(192, 4) void ms_fused(const float* __restrict__ in,
                                                   float* __restrict__ out,
                                                   float* __restrict__ ws) {
    __shared__ __align__(16) float tile[LH * LS];
    __shared__ float4 part[4][48];

    cg::grid_group grid = cg::this_grid();

    const int b   = blockIdx.z;
    const int bx0 = blockIdx.x * TW;
    const int by0 = blockIdx.y * TH;

    const int tid = threadIdx.x;     // 0..191
    const int tz  = tid / 48;        // 0..3   dy group
    const int p   = tid - 48 * tz;   // 0..47  pixel-pair slot
    const int tx  = p & 7;           // pair col 0..7
    const int ty  = p >> 3;          // row 0..5

    // CX[dx] = (1/(0.5*sqrt(2pi))) * exp(-(dx-9)^2/144)   (range amp * spatial-x)
    constexpr float CX[SD] = {
        0.45461166f, 0.51157701f, 0.56774066f, 0.62138379f, 0.67071069f,
        0.71397332f, 0.74953931f, 0.77602279f, 0.79236573f, 0.79788456f,
        0.79236573f, 0.77602279f, 0.74953931f, 0.71397332f, 0.67071069f,
        0.62138379f, 0.56774066f, 0.51157701f, 0.45461166f
    };
    const float RSIG = 1.69864365f;    // sqrt(2*log2(e)): exp(-2d^2) = exp2(-(d*RSIG)^2)
    const float THR  = 0.60653066f;    // exp(-1/2): range-weight zero crossing

    const int beg = 5 * tz;                    // {0,5,10,15}
    const int nr  = (tz == 3) ? 4 : 5;         // rows per group: {5,5,5,4}
    const int x0  = 2 * tx;

    const float* src = in;
    float*       dst = out;

    for (int it = 0; it < 3; ++it) {
        // ---- stage padded tile (replication pad via clamp) ----
        const float* __restrict__ img = src + b * NPIX;
        for (int i = tid; i < LH * LW; i += 192) {
            int r  = i / LW, c = i - r * LW;
            int gy = min(max(by0 + r - SR, 0), IMG - 1);
            int gx = min(max(bx0 + c - SR, 0), IMG - 1);
            tile[r * LS + c] = img[gy * IMG + gx];
        }
        __syncthreads();

        const float cA  = tile[(ty + SR) * LS + x0 + SR];
        const float cB  = tile[(ty + SR) * LS + x0 + SR + 1];
        const float crA = cA * RSIG;
        const float crB = cB * RSIG;

        float numA = 0.f, denA = 0.f, numB = 0.f, denB = 0.f;
        for (int r = 0; r < nr; ++r) {
            const int   dy = beg + r;
            const float ft = (float)(dy - SR);
            const float fy = __builtin_amdgcn_exp2f(ft * ft * -0.010018715f);

            const float2* r2 = reinterpret_cast<const float2*>(&tile[(ty + dy) * LS + x0]);
            float w20[20];
#pragma unroll
            for (int j = 0; j < 10; ++j) { float2 v = r2[j]; w20[2*j] = v.x; w20[2*j+1] = v.y; }

            float rnA = 0.f, rdA = 0.f, rnB = 0.f, rdB = 0.f;
#pragma unroll
            for (int dx = 0; dx < SD; ++dx) {
                float nA = w20[dx], nB = w20[dx + 1];
                float sA = fmaf(nA, -RSIG, crA);
                float sB = fmaf(nB, -RSIG, crB);
                float eA = __builtin_amdgcn_exp2f(-sA * sA);
                float eB = __builtin_amdgcn_exp2f(-sB * sB);
                float tA = fmaxf(eA - THR, 0.f);          // VOP2 literal-friendly form
                float tB = fmaxf(eB - THR, 0.f);
                float wA = CX[dx] * tA;
                float wB = CX[dx] * tB;
                rnA = fmaf(wA, nA, rnA); rdA += wA;
                rnB = fmaf(wB, nB, rnB); rdB += wB;
            }
            numA = fmaf(fy, rnA, numA); denA = fmaf(fy, rdA, denA);
            numB = fmaf(fy, rnB, numB); denB = fmaf(fy, rdB, denB);
        }

        part[tz][p] = make_float4(numA, denA, numB, denB);
        __syncthreads();

        if (tid < 48) {
            float4 p0 = part[0][tid], p1 = part[1][tid];
            float4 p2 = part[2][tid], p3 = part[3][tid];
            float nA = p0.x + p1.x + p2.x + p3.x;
            float dA = p0.y + p1.y + p2.y + p3.y;
            float nB = p0.z + p1.z + p2.z + p3.z;
            float dB = p0.w + p1.w + p2.w + p3.w;
            const float K = 0.04701581f;   // 1/(SSIGMA*sqrt(2pi)) (spatial amplitude)
            float2 o;
            o.x = (K * nA) / (K * dA + 1e-8f);
            o.y = (K * nB) / (K * dB + 1e-8f);
            const int otx = tid & 7, oty = tid >> 3;
            *reinterpret_cast<float2*>(&dst[b * NPIX + (by0 + oty) * IMG + bx0 + 2 * otx]) = o;
        }

        if (it < 2) grid.sync();           // includes block barrier + device-scope visibility
        src = (it == 0) ? out : ws;
        dst = (it == 0) ? ws  : out;
    }
}

extern "C" void kernel_launch(void* const* d_in, const int* in_sizes, int n_in,
                              void* d_out, int out_size, void* d_ws, size_t ws_size,
                              hipStream_t stream) {
    const float* in  = (const float*)d_in[0];
    float*       out = (float*)d_out;
    float*       ws  = (float*)d_ws;   // needs 2*192*192*4 = 294912 bytes

    dim3 grid(IMG / TW, IMG / TH, 2);   // 12 x 32 x 2 = 768 blocks = 3/CU exactly
    dim3 block(192, 1, 1);              // 3 waves

    void* args[] = { (void*)&in, (void*)&out, (void*)&ws };
    hipLaunchCooperativeKernel((const void*)ms_fused, grid, block, args, 0, stream);
}

// Round 5
// 34.067 us; speedup vs baseline: 5.2837x; 5.2837x over previous
//
#include <hip/hip_runtime.h>

#define SR   9
#define SD   19
#define TW   16                 // tile width (pixels)
#define TH   4                  // tile height (pixels)
#define LW   (TW + 2*SR)        // 34 staged cols
#define LH   (TH + 2*SR)        // 22 staged rows
#define LS   42                 // LDS row stride; 42%32=10 -> spread rows across banks
#define IMG  192
#define NPIX (IMG*IMG)

__global__ __launch_bounds__(192, 4) void ms_iter(const float* __restrict__ in,
                                                  float* __restrict__ out) {
    __shared__ __align__(16) float tile[LH * LS];
    __shared__ float4 pn[3][16], pd[3][16];

    const int b   = blockIdx.z;
    const int bx0 = blockIdx.x * TW;
    const int by0 = blockIdx.y * TH;
    const float* __restrict__ img = in + b * NPIX;

    const int tx  = threadIdx.x;            // 0..3  quad column
    const int ty  = threadIdx.y;            // 0..3  pixel row
    const int tz  = threadIdx.z;            // 0..11 dy group
    const int tid = tx + 4*ty + 16*tz;      // 0..191

    // stage padded tile (replication pad via clamp)
    for (int i = tid; i < LH*LW; i += 192) {
        int r  = i / LW, c = i - r*LW;
        int gy = min(max(by0 + r - SR, 0), IMG-1);
        int gx = min(max(bx0 + c - SR, 0), IMG-1);
        tile[r*LS + c] = img[gy*IMG + gx];
    }
    __syncthreads();

    // log-folded constants:
    // LCX[dx]  = log2( 0.7978845608 * exp(-(dx-9)^2/144) )
    // CTHR[dx] = exp(-1/2) * 0.7978845608 * exp(-(dx-9)^2/144)
    constexpr float LCX[SD] = {
        -1.1374483f, -0.9671302f, -0.8168495f, -0.6866062f, -0.5764004f,
        -0.4862319f, -0.4161009f, -0.3660074f, -0.3359512f, -0.3259325f,
        -0.3359512f, -0.3660074f, -0.4161009f, -0.4862319f, -0.5764004f,
        -0.6866062f, -0.8168495f, -0.9671302f, -1.1374483f
    };
    constexpr float CTHR[SD] = {
        0.2757359f, 0.3102872f, 0.3443521f, 0.3768883f, 0.4068066f,
        0.4330467f, 0.4546185f, 0.4706816f, 0.4805941f, 0.4839414f,
        0.4805941f, 0.4706816f, 0.4546185f, 0.4330467f, 0.4068066f,
        0.3768883f, 0.3443521f, 0.3102872f, 0.2757359f
    };
    const float RSIG = 1.69864365f;   // sqrt(2*log2 e): exp(-2d^2)=exp2(-(d*RSIG)^2)

    const int x0 = 4*tx;
    float cr[4];
#pragma unroll
    for (int p = 0; p < 4; ++p)
        cr[p] = tile[(ty+SR)*LS + x0 + SR + p] * RSIG;

    // dy groups: tz 0-7 -> 2 rows each (rows 0..15), tz 8-10 -> 1 row (16..18), tz 11 idle.
    // Waves 0,1 are row-count uniform; wave 2 pays one masked slot.
    const int beg = (tz < 8) ? 2*tz : (8 + tz);
    const int nr  = (tz < 8) ? 2 : ((tz < 11) ? 1 : 0);

    float num[4] = {0.f,0.f,0.f,0.f}, den[4] = {0.f,0.f,0.f,0.f};
    for (int r = 0; r < nr; ++r) {
        const int   dy = beg + r;
        const float ft = (float)(dy - SR);
        const float fy = __builtin_amdgcn_exp2f(ft * ft * -0.010018715f);

        const float2* r2 = reinterpret_cast<const float2*>(&tile[(ty+dy)*LS + x0]);
        float w[22];
#pragma unroll
        for (int j = 0; j < 11; ++j) { float2 v = r2[j]; w[2*j] = v.x; w[2*j+1] = v.y; }

        float rn[4] = {0.f,0.f,0.f,0.f}, rd[4] = {0.f,0.f,0.f,0.f};
#pragma unroll
        for (int dx = 0; dx < SD; ++dx) {
#pragma unroll
            for (int p = 0; p < 4; ++p) {
                float nv = w[dx + p];
                float s  = fmaf(nv, -RSIG, cr[p]);
                float e  = __builtin_amdgcn_exp2f(fmaf(-s, s, LCX[dx]));
                float wt = fmaxf(e - CTHR[dx], 0.f);
                rn[p] = fmaf(wt, nv, rn[p]);
                rd[p] += wt;
            }
        }
#pragma unroll
        for (int p = 0; p < 4; ++p) {
            num[p] = fmaf(fy, rn[p], num[p]);
            den[p] = fmaf(fy, rd[p], den[p]);
        }
    }

    // reduce across the 4 tz' groups sharing each wave (lane bits 4-5)
#pragma unroll
    for (int p = 0; p < 4; ++p) {
        num[p] += __shfl_xor(num[p], 16); num[p] += __shfl_xor(num[p], 32);
        den[p] += __shfl_xor(den[p], 16); den[p] += __shfl_xor(den[p], 32);
    }

    const int lane = tid & 63;
    const int wv   = tid >> 6;            // 0..2
    if (lane < 16) {
        pn[wv][lane] = make_float4(num[0], num[1], num[2], num[3]);
        pd[wv][lane] = make_float4(den[0], den[1], den[2], den[3]);
    }
    __syncthreads();

    // final cross-wave combine + normalize: 64 threads, one pixel each
    if (tid < 64) {
        const int px = tid & 3, slot = tid >> 2;         // slot = tx + 4*ty
        const float* n0 = (const float*)&pn[0][slot];
        const float* n1 = (const float*)&pn[1][slot];
        const float* n2 = (const float*)&pn[2][slot];
        const float* d0 = (const float*)&pd[0][slot];
        const float* d1 = (const float*)&pd[1][slot];
        const float* d2 = (const float*)&pd[2][slot];
        float n = n0[px] + n1[px] + n2[px];
        float d = d0[px] + d1[px] + d2[px];
        const float K = 0.04701581f;   // 1/(SSIGMA*sqrt(2pi)) (spatial amplitude)
        out[b*NPIX + (by0 + (slot >> 2))*IMG + bx0 + 4*(slot & 3) + px]
            = (K * n) / (K * d + 1e-8f);
    }
}

extern "C" void kernel_launch(void* const* d_in, const int* in_sizes, int n_in,
                              void* d_out, int out_size, void* d_ws, size_t ws_size,
                              hipStream_t stream) {
    const float* in  = (const float*)d_in[0];
    float*       out = (float*)d_out;
    float*       ws  = (float*)d_ws;   // needs 2*192*192*4 = 294912 bytes

    dim3 grid(IMG / TW, IMG / TH, 2);   // 12 x 48 x 2 = 1152 blocks
    dim3 block(4, 4, 12);               // 192 threads = 3 waves

    ms_iter<<<grid, block, 0, stream>>>(in, out);   // iter 1
    ms_iter<<<grid, block, 0, stream>>>(out, ws);   // iter 2
    ms_iter<<<grid, block, 0, stream>>>(ws, out);   // iter 3
}

// Round 6
// 30.786 us; speedup vs baseline: 5.8469x; 1.1066x over previous
//
#include <hip/hip_runtime.h>

#define SR   9
#define SD   19
#define TW   16                 // tile width (pixels)
#define TH   4                  // tile height (pixels)
#define LW   (TW + 2*SR)        // 34 staged cols
#define LH   (TH + 2*SR)        // 22 staged rows
#define LS   42                 // LDS row stride; odd mod-32 spread
#define IMG  192
#define NPIX (IMG*IMG)

// Block = 512 threads = 8 waves. thread = (slot, tz): slot = 32 pixel-pairs
// (8 pair-cols x 4 rows), tz = 16 dy-groups. VGPR pinned <=64 via
// __launch_bounds__(512,8) so 4 blocks (32 waves) reside per CU.
__global__ __launch_bounds__(512, 8) void ms_iter(const float* __restrict__ in,
                                                  float* __restrict__ out) {
    __shared__ __align__(16) float tile[LH * LS];
    __shared__ float4 part[16][32];

    const int b   = blockIdx.z;
    const int bx0 = blockIdx.x * TW;
    const int by0 = blockIdx.y * TH;
    const float* __restrict__ img = in + b * NPIX;

    const int tid  = threadIdx.x;     // 0..511
    const int slot = tid & 31;        // pixel-pair slot
    const int tz   = tid >> 5;        // 0..15 dy group
    const int tx   = slot & 7;        // pair col
    const int ty   = slot >> 3;       // pixel row 0..3

    // stage padded tile (replication pad via clamp)
    for (int i = tid; i < LH * LW; i += 512) {
        int r  = i / LW, c = i - r * LW;
        int gy = min(max(by0 + r - SR, 0), IMG - 1);
        int gx = min(max(bx0 + c - SR, 0), IMG - 1);
        tile[r * LS + c] = img[gy * IMG + gx];
    }
    __syncthreads();

    // log-folded constants:
    // LCX[dx]  = log2( 0.7978845608 * exp(-(dx-9)^2/144) )
    // CTHR[dx] = exp(-1/2) * 0.7978845608 * exp(-(dx-9)^2/144)
    constexpr float LCX[SD] = {
        -1.1374483f, -0.9671302f, -0.8168495f, -0.6866062f, -0.5764004f,
        -0.4862319f, -0.4161009f, -0.3660074f, -0.3359512f, -0.3259325f,
        -0.3359512f, -0.3660074f, -0.4161009f, -0.4862319f, -0.5764004f,
        -0.6866062f, -0.8168495f, -0.9671302f, -1.1374483f
    };
    constexpr float CTHR[SD] = {
        0.2757359f, 0.3102872f, 0.3443521f, 0.3768883f, 0.4068066f,
        0.4330467f, 0.4546185f, 0.4706816f, 0.4805941f, 0.4839414f,
        0.4805941f, 0.4706816f, 0.4546185f, 0.4330467f, 0.4068066f,
        0.3768883f, 0.3443521f, 0.3102872f, 0.2757359f
    };
    const float RSIG = 1.69864365f;   // sqrt(2*log2 e): exp(-2d^2)=exp2(-(d*RSIG)^2)

    const int   x0  = 2 * tx;
    const float crA = tile[(ty + SR) * LS + x0 + SR]     * RSIG;
    const float crB = tile[(ty + SR) * LS + x0 + SR + 1] * RSIG;

    // dy rows per tz: tz 0..2 -> 2 rows (0..5), tz 3..15 -> 1 row (6..18).
    // Waves: {tz0,tz1}=2,2 ; {tz2,tz3}=2,1 (one mixed) ; rest uniform 1.
    const int beg = (tz < 3) ? 2 * tz : (tz + 3);
    const int nr  = (tz < 3) ? 2 : 1;

    float numA = 0.f, denA = 0.f, numB = 0.f, denB = 0.f;
    for (int r = 0; r < nr; ++r) {
        const int   dy = beg + r;
        const float ft = (float)(dy - SR);
        const float fy = __builtin_amdgcn_exp2f(ft * ft * -0.010018715f);

        const float2* r2 = reinterpret_cast<const float2*>(&tile[(ty + dy) * LS + x0]);
        float w[20];
#pragma unroll
        for (int j = 0; j < 10; ++j) { float2 v = r2[j]; w[2*j] = v.x; w[2*j+1] = v.y; }

        float rnA = 0.f, rdA = 0.f, rnB = 0.f, rdB = 0.f;
#pragma unroll
        for (int dx = 0; dx < SD; ++dx) {
            float nA = w[dx], nB = w[dx + 1];
            float sA = fmaf(nA, -RSIG, crA);
            float sB = fmaf(nB, -RSIG, crB);
            float eA = __builtin_amdgcn_exp2f(fmaf(-sA, sA, LCX[dx]));
            float eB = __builtin_amdgcn_exp2f(fmaf(-sB, sB, LCX[dx]));
            // wt in [0, 0.32] always -> fmin(fmax(x,0),1) == max(x,0); the
            // [0,1] clamp pattern folds into the sub's clamp modifier.
            float wA = fminf(fmaxf(eA - CTHR[dx], 0.f), 1.f);
            float wB = fminf(fmaxf(eB - CTHR[dx], 0.f), 1.f);
            rnA = fmaf(wA, nA, rnA); rdA += wA;
            rnB = fmaf(wB, nB, rnB); rdB += wB;
        }
        numA = fmaf(fy, rnA, numA); denA = fmaf(fy, rdA, denA);
        numB = fmaf(fy, rnB, numB); denB = fmaf(fy, rdB, denB);
    }

    part[tz][slot] = make_float4(numA, denA, numB, denB);
    __syncthreads();

    // final combine: 32 threads, one pixel-pair each
    if (tid < 32) {
        float nA = 0.f, dA = 0.f, nB = 0.f, dB = 0.f;
#pragma unroll
        for (int g = 0; g < 16; ++g) {
            float4 v = part[g][tid];
            nA += v.x; dA += v.y; nB += v.z; dB += v.w;
        }
        const float K = 0.04701581f;   // 1/(SSIGMA*sqrt(2pi)) (spatial amplitude)
        float2 o;
        o.x = (K * nA) / (K * dA + 1e-8f);
        o.y = (K * nB) / (K * dB + 1e-8f);
        const int otx = tid & 7, oty = tid >> 3;
        *reinterpret_cast<float2*>(&out[b * NPIX + (by0 + oty) * IMG + bx0 + 2 * otx]) = o;
    }
}

extern "C" void kernel_launch(void* const* d_in, const int* in_sizes, int n_in,
                              void* d_out, int out_size, void* d_ws, size_t ws_size,
                              hipStream_t stream) {
    const float* in  = (const float*)d_in[0];
    float*       out = (float*)d_out;
    float*       ws  = (float*)d_ws;   // needs 2*192*192*4 = 294912 bytes

    dim3 grid(IMG / TW, IMG / TH, 2);   // 12 x 48 x 2 = 1152 blocks
    dim3 block(512, 1, 1);              // 8 waves

    ms_iter<<<grid, block, 0, stream>>>(in, out);   // iter 1
    ms_iter<<<grid, block, 0, stream>>>(out, ws);   // iter 2
    ms_iter<<<grid, block, 0, stream>>>(ws, out);   // iter 3
}